// Round 1
// baseline (816.726 us; speedup 1.0000x reference)
//
#include <hip/hip_runtime.h>
#include <cstdint>
#include <cstddef>

typedef _Float16 f16;
typedef _Float16 half8 __attribute__((ext_vector_type(8)));
typedef _Float16 half4 __attribute__((ext_vector_type(4)));
typedef float float4v __attribute__((ext_vector_type(4)));

static __device__ __forceinline__ float4v mfma16(half8 a, half8 b, float4v c) {
  return __builtin_amdgcn_mfma_f32_16x16x32_f16(a, b, c, 0, 0, 0);
}

// ---------------------------------------------------------------------------
// gemm_u: OUT[row, outcol+g] = sum_k A[row*ldA + k] * W[g*K + k] + bias[g]
// M = 65536 rows, N = 256 features, K in {32, 256}.
// Split-f16 (hi+lo for A and W) -> ~fp32-accurate products. The ESN input
// path has per-layer gain ~||W_i row|| ~ 9.2, so this GEMM must be accurate.
// Block tile: 128 M x 256 N, 4 waves (wave = 32 M rows x 256 N).
// LDS fragment layout [tile][quad][m|n][j] so ds_read_b128 is conflict-free.
// ---------------------------------------------------------------------------
__global__ __launch_bounds__(256, 2) void gemm_u(
    const float* __restrict__ A, int ldA, int K,
    const float* __restrict__ W,
    const float* __restrict__ bias,
    float* __restrict__ outp, int outcol)
{
  __shared__ alignas(16) f16 Ah[4096];
  __shared__ alignas(16) f16 Al[4096];
  __shared__ alignas(16) f16 Bh[8192];
  __shared__ alignas(16) f16 Bl[8192];

  const int tid = threadIdx.x;
  const int w = tid >> 6, lane = tid & 63, q = lane >> 4, c = lane & 15;
  const int mbase = blockIdx.x * 128;
  const int seg = tid & 7, rbase = tid >> 3;

  float4v acc[2][16] = {};
  const int nchunk = K >> 5;

  for (int kc = 0; kc < nchunk; ++kc) {
    // ---- stage A chunk: 128 rows x 32 k, fp32 -> split f16
    #pragma unroll
    for (int it = 0; it < 4; ++it) {
      int row = it * 32 + rbase;                 // 0..127
      const float* src = A + (size_t)(mbase + row) * ldA + kc * 32 + seg * 4;
      float4v v = *(const float4v*)src;
      f16 h0 = (f16)v.x, h1 = (f16)v.y, h2 = (f16)v.z, h3 = (f16)v.w;
      half4 hi = {h0, h1, h2, h3};
      half4 lo = {(f16)(v.x - (float)h0), (f16)(v.y - (float)h1),
                  (f16)(v.z - (float)h2), (f16)(v.w - (float)h3)};
      int mt = row >> 4, m = row & 15, qq = seg >> 1, jj = (seg & 1) * 4;
      int ofs = ((mt * 4 + qq) * 16 + m) * 8 + jj;
      *(half4*)&Ah[ofs] = hi;
      *(half4*)&Al[ofs] = lo;
    }
    // ---- stage B chunk: 256 g-rows x 32 k
    #pragma unroll
    for (int it = 0; it < 8; ++it) {
      int g = it * 32 + rbase;                   // 0..255
      const float* src = W + (size_t)g * K + kc * 32 + seg * 4;
      float4v v = *(const float4v*)src;
      f16 h0 = (f16)v.x, h1 = (f16)v.y, h2 = (f16)v.z, h3 = (f16)v.w;
      half4 hi = {h0, h1, h2, h3};
      half4 lo = {(f16)(v.x - (float)h0), (f16)(v.y - (float)h1),
                  (f16)(v.z - (float)h2), (f16)(v.w - (float)h3)};
      int nt = g >> 4, n = g & 15, qq = seg >> 1, jj = (seg & 1) * 4;
      int ofs = ((nt * 4 + qq) * 16 + n) * 8 + jj;
      *(half4*)&Bh[ofs] = hi;
      *(half4*)&Bl[ofs] = lo;
    }
    __syncthreads();

    half8 ah[2], al[2];
    #pragma unroll
    for (int m2 = 0; m2 < 2; ++m2) {
      int mt = w * 2 + m2;
      int ofs = ((mt * 4 + q) * 16 + c) * 8;
      ah[m2] = *(half8*)&Ah[ofs];
      al[m2] = *(half8*)&Al[ofs];
    }
    #pragma unroll
    for (int nt = 0; nt < 16; ++nt) {
      int ofs = ((nt * 4 + q) * 16 + c) * 8;
      half8 bh = *(half8*)&Bh[ofs];
      half8 bl = *(half8*)&Bl[ofs];
      #pragma unroll
      for (int m2 = 0; m2 < 2; ++m2) {
        acc[m2][nt] = mfma16(ah[m2], bh, acc[m2][nt]);
        acc[m2][nt] = mfma16(al[m2], bh, acc[m2][nt]);
        acc[m2][nt] = mfma16(ah[m2], bl, acc[m2][nt]);
      }
    }
    __syncthreads();
  }

  // ---- epilogue: C layout col = lane&15, row = quad*4 + reg
  #pragma unroll
  for (int m2 = 0; m2 < 2; ++m2) {
    #pragma unroll
    for (int nt = 0; nt < 16; ++nt) {
      int g = nt * 16 + c;
      float b = bias[g];
      #pragma unroll
      for (int i = 0; i < 4; ++i) {
        int row = mbase + w * 32 + m2 * 16 + q * 4 + i;
        outp[(size_t)row * 768 + outcol + g] = acc[m2][nt][i] + b;
      }
    }
  }
}

// ---------------------------------------------------------------------------
// rec_layer: leaky-integrator recurrence for one layer.
//   h_t = 0.1*h_{t-1} + 0.9*tanh(u_t + h_{t-1} @ W_hh^T)
// Grid: 32 blocks x 256 threads. Block owns 16 sequences (rows r0..r0+15,
// r = b*64+n). Wave w owns output features [w*64, w*64+64) = 4 N-tiles.
// W_hh is held in registers as B-fragments (128 VGPRs/wave) -> no LDS
// traffic for weights in the 128-step loop. h round-trips through an 8 KB
// LDS buffer in exact A-fragment order [kc][quad][m][j].
// u is read from d_out's own column slice and overwritten with h in-place
// (same lane reads u before writing h at the same address).
// ---------------------------------------------------------------------------
__global__ __launch_bounds__(256, 1) void rec_layer(
    float* __restrict__ io, const float* __restrict__ whh, int outcol)
{
  __shared__ alignas(16) f16 hl[4096];   // [kc(8)][quad(4)][m(16)][j(8)]

  const int tid = threadIdx.x;
  const int w = tid >> 6, lane = tid & 63, q = lane >> 4, c = lane & 15;
  const int r0 = blockIdx.x * 16;

  // preload W_hh B-fragments: wf[tn][kc] -> B[k = kc*32+q*8+j][n] = W[g][k]
  half8 wf[4][8];
  #pragma unroll
  for (int tn = 0; tn < 4; ++tn) {
    const int g = w * 64 + tn * 16 + c;
    #pragma unroll
    for (int kc = 0; kc < 8; ++kc) {
      const float* src = whh + (size_t)g * 256 + kc * 32 + q * 8;
      float4v v0 = *(const float4v*)src;
      float4v v1 = *(const float4v*)(src + 4);
      half8 h = {(f16)v0.x, (f16)v0.y, (f16)v0.z, (f16)v0.w,
                 (f16)v1.x, (f16)v1.y, (f16)v1.z, (f16)v1.w};
      wf[tn][kc] = h;
    }
  }

  // zero the h LDS buffer (h0 = 0)
  {
    uint32_t* p = (uint32_t*)hl;
    #pragma unroll
    for (int i = 0; i < 8; ++i) p[tid + i * 256] = 0u;
  }

  float hreg[4][4] = {};     // persistent h in C layout (fp32)
  size_t base[4];            // per-reg global address base (t = 0)
  #pragma unroll
  for (int i = 0; i < 4; ++i) {
    const int m = q * 4 + i;
    const int r = r0 + m;
    const int bb = r >> 6, nn = r & 63;
    base[i] = ((size_t)bb * 8192 + nn) * 768 + outcol + w * 64 + c;
  }
  __syncthreads();

  // u for t=0
  float uv[4][4];
  #pragma unroll
  for (int tn = 0; tn < 4; ++tn)
    #pragma unroll
    for (int i = 0; i < 4; ++i)
      uv[tn][i] = io[base[i] + tn * 16];

  for (int t = 0; t < 128; ++t) {
    // A-fragments of h_{t-1} (conflict-free ds_read_b128)
    half8 af[8];
    #pragma unroll
    for (int kc = 0; kc < 8; ++kc)
      af[kc] = *(half8*)&hl[((kc * 4 + q) * 16 + c) * 8];

    // prefetch next step's u (hides HBM latency under the MFMAs)
    const size_t tofs = (size_t)(t < 127 ? t + 1 : t) * 49152;  // 64*768
    float uvn[4][4];
    #pragma unroll
    for (int tn = 0; tn < 4; ++tn)
      #pragma unroll
      for (int i = 0; i < 4; ++i)
        uvn[tn][i] = io[base[i] + tofs + tn * 16];

    // rec = h_{t-1} @ W_hh^T : 32 MFMAs, 4 independent acc chains
    float4v acc[4] = {};
    #pragma unroll
    for (int kc = 0; kc < 8; ++kc) {
      #pragma unroll
      for (int tn = 0; tn < 4; ++tn)
        acc[tn] = mfma16(af[kc], wf[tn][kc], acc[tn]);
    }
    __syncthreads();   // all waves done reading hl before rewrite

    const size_t sofs = (size_t)t * 49152;
    #pragma unroll
    for (int tn = 0; tn < 4; ++tn) {
      const int gcol = w * 64 + tn * 16 + c;
      const int widx = (((gcol >> 5) * 4 + ((gcol >> 3) & 3)) * 16) * 8 + (gcol & 7);
      #pragma unroll
      for (int i = 0; i < 4; ++i) {
        const float xv = uv[tn][i] + acc[tn][i];
        const float e  = __expf(2.0f * xv);
        const float th = 1.0f - 2.0f / (e + 1.0f);      // tanh(xv)
        const float hn = 0.1f * hreg[tn][i] + 0.9f * th;
        hreg[tn][i] = hn;
        io[base[i] + sofs + tn * 16] = hn;              // overwrite u with h
        const int m = q * 4 + i;
        hl[widx + m * 8] = (f16)hn;                     // A-layout for t+1
      }
    }
    #pragma unroll
    for (int tn = 0; tn < 4; ++tn)
      #pragma unroll
      for (int i = 0; i < 4; ++i)
        uv[tn][i] = uvn[tn][i];
    __syncthreads();
  }
}

// ---------------------------------------------------------------------------
// Launch: u for layer l is materialized in d_out's own column slice
// [l*256, (l+1)*256), then rec_layer consumes and overwrites it in place.
// d_ws is unused.
// ---------------------------------------------------------------------------
extern "C" void kernel_launch(void* const* d_in, const int* in_sizes, int n_in,
                              void* d_out, int out_size, void* d_ws, size_t ws_size,
                              hipStream_t stream) {
  (void)in_sizes; (void)n_in; (void)out_size; (void)d_ws; (void)ws_size;
  const float* x     = (const float*)d_in[0];   // [8,128,64,32]
  const float* w_ih0 = (const float*)d_in[1];   // [256,32]
  const float* w_ih  = (const float*)d_in[2];   // [2,256,256]
  const float* b_ih  = (const float*)d_in[3];   // [3,256]
  const float* w_hh  = (const float*)d_in[4];   // [3,256,256]
  float* out = (float*)d_out;                   // [8,128,64,768] fp32

  // layer 0
  gemm_u<<<512, 256, 0, stream>>>(x,        32,  32, w_ih0,         b_ih,       out, 0);
  rec_layer<<<32, 256, 0, stream>>>(out, w_hh,            0);
  // layer 1
  gemm_u<<<512, 256, 0, stream>>>(out,      768, 256, w_ih,          b_ih + 256, out, 256);
  rec_layer<<<32, 256, 0, stream>>>(out, w_hh + 65536,    256);
  // layer 2
  gemm_u<<<512, 256, 0, stream>>>(out + 256, 768, 256, w_ih + 65536, b_ih + 512, out, 512);
  rec_layer<<<32, 256, 0, stream>>>(out, w_hh + 131072,   512);
}